// Round 12
// baseline (267.049 us; speedup 1.0000x reference)
//
#include <hip/hip_runtime.h>
#include <stdint.h>
#include <math.h>

#define D_IN   1024
#define NQKV   3072
#define NHEADS 16
#define DH     64
#define BATCH  4
#define SEQ    2048
#define MTOT   (BATCH*SEQ)   // 8192

typedef __bf16    bf16x8 __attribute__((ext_vector_type(8)));
typedef _Float16  f16x8  __attribute__((ext_vector_type(8)));
typedef float     f32x4  __attribute__((ext_vector_type(4)));
typedef float     f32x16 __attribute__((ext_vector_type(16)));

typedef __attribute__((address_space(3))) unsigned short       lds_us;
typedef __attribute__((address_space(1))) const unsigned short glb_us;

__device__ __forceinline__ unsigned short f2bf(float f) {
    union { float f; uint32_t u; } c; c.f = f;
    uint32_t u = c.u;
    uint32_t r = u + 0x7fffu + ((u >> 16) & 1u);  // RNE
    return (unsigned short)(r >> 16);
}
__device__ __forceinline__ uint32_t pkh(float a, float b) {
    auto h = __builtin_amdgcn_cvt_pkrtz(a, b);   // __fp16 ext_vector(2): low=a, high=b
    uint32_t u;
    __builtin_memcpy(&u, &h, 4);
    return u;
}

// ---------------- stage 0a: x fp32 -> bf16 ----------------
__global__ void k_convert_x(const float* __restrict__ x, unsigned short* __restrict__ xb) {
    int i = blockIdx.x * 256 + threadIdx.x;
    float4 v = ((const float4*)x)[i];
    ushort4 o;
    o.x = f2bf(v.x); o.y = f2bf(v.y); o.z = f2bf(v.z); o.w = f2bf(v.w);
    ((ushort4*)xb)[i] = o;
}

// ---------------- stage 0b: W fp32 [K][N] -> Wt bf16 [N][K] ----------------
__global__ void k_convert_wt(const float* __restrict__ W, unsigned short* __restrict__ Wt) {
    __shared__ float tile[32][33];
    int tx = threadIdx.x, ty = threadIdx.y;
    int n0 = blockIdx.x * 32, k0 = blockIdx.y * 32;
    #pragma unroll
    for (int i = 0; i < 4; ++i) {
        int k = k0 + ty + i*8;
        tile[ty + i*8][tx] = W[(size_t)k * NQKV + n0 + tx];
    }
    __syncthreads();
    #pragma unroll
    for (int i = 0; i < 4; ++i) {
        int n = n0 + ty + i*8;
        Wt[(size_t)n * D_IN + k0 + tx] = f2bf(tile[tx][ty + i*8]);
    }
}

// ---------------- stage 1: QKV GEMM with FRAGMENT-SCATTER epilogue ----------------
// (unchanged from R8 — verified passing) Writes Qbuf/Kfrag/Vfrag in the exact
// per-lane fragment order k_attn consumes; every k_attn in-loop load is a fully
// coalesced 1KB wave-read. Elem->key placements identical to the R6-verified math.
__global__ __launch_bounds__(256) void k_gemm_qkv(
    const unsigned short* __restrict__ A,   // [8192][1024] bf16
    const unsigned short* __restrict__ Bt,  // [3072][1024] bf16
    const float* __restrict__ bias,         // [3072]
    unsigned short* __restrict__ Qb,        // [8192][1024] bf16
    unsigned short* __restrict__ Kf,        // fragment layout, 8M shorts
    unsigned short* __restrict__ Vf)        // fragment layout, 8M shorts (f16)
{
    __shared__ __align__(16) unsigned short As[128*32];
    __shared__ __align__(16) unsigned short Bs[128*32];
    const int t = threadIdx.x;
    const int wave = t >> 6, lane = t & 63, quad = lane >> 4, l15 = lane & 15;
    const int wm = wave >> 1, wn = wave & 1;
    const int m0 = blockIdx.y * 128, n0 = blockIdx.x * 128;
    const int crow = lane >> 2;          // row within 16-row chunk
    const int ccol = (lane & 3) << 3;    // short col within row

    f32x4 acc[4][4] = {};
    lds_us* As3 = (lds_us*)As;
    lds_us* Bs3 = (lds_us*)Bs;

    for (int k0 = 0; k0 < D_IN; k0 += 32) {
        #pragma unroll
        for (int j = 0; j < 2; ++j) {
            int chunk = wave*2 + j;
            const unsigned short* ga = A  + (size_t)(m0 + chunk*16 + crow)*D_IN + k0 + ccol;
            const unsigned short* gb = Bt + (size_t)(n0 + chunk*16 + crow)*D_IN + k0 + ccol;
            __builtin_amdgcn_global_load_lds((glb_us*)ga, As3 + chunk*512, 16, 0, 0);
            __builtin_amdgcn_global_load_lds((glb_us*)gb, Bs3 + chunk*512, 16, 0, 0);
        }
        __syncthreads();
        bf16x8 a[4], b[4];
        #pragma unroll
        for (int tm = 0; tm < 4; ++tm)
            a[tm] = *(const bf16x8*)(&As[(wm*64 + tm*16 + l15)*32 + quad*8]);
        #pragma unroll
        for (int tn = 0; tn < 4; ++tn)
            b[tn] = *(const bf16x8*)(&Bs[(wn*64 + tn*16 + l15)*32 + quad*8]);
        #pragma unroll
        for (int tm = 0; tm < 4; ++tm)
            #pragma unroll
            for (int tn = 0; tn < 4; ++tn)
                acc[tm][tn] = __builtin_amdgcn_mfma_f32_16x16x32_bf16(a[tm], b[tn], acc[tm][tn], 0, 0, 0);
        __syncthreads();
    }
    const float qs = 0.125f * 1.44269504089f;
    #pragma unroll
    for (int tn = 0; tn < 4; ++tn) {
        const int col0 = n0 + wn*64 + tn*16;     // lane-uniform
        const int h   = col0 / 192;
        const int r0  = col0 - h*192;            // 0..191, run of 16 stays in one kind
        const float bv = bias[col0 + l15];
        if (r0 < 64) {
            // ---- Q: Qbuf[row][h*64 + dk], scaled ----
            const int dk = r0 + l15;
            #pragma unroll
            for (int tm = 0; tm < 4; ++tm)
                #pragma unroll
                for (int r = 0; r < 4; ++r) {
                    int row = m0 + wm*64 + tm*16 + quad*4 + r;
                    Qb[(size_t)row*1024 + h*64 + dk] = f2bf((acc[tm][tn][r] + bv) * qs);
                }
        } else if (r0 < 128) {
            // ---- K fragment scatter ----
            const int dk = r0 - 64 + l15;
            const int st = dk >> 4, hi2 = (dk >> 3) & 1, j = dk & 7;
            #pragma unroll
            for (int tm = 0; tm < 4; ++tm)
                #pragma unroll
                for (int r = 0; r < 4; ++r) {
                    int row = m0 + wm*64 + tm*16 + quad*4 + r;
                    int bh = ((row >> 11) << 4) + h;
                    int chunk = (row >> 5) & 63, l31r = row & 31;
                    Kf[((size_t)(bh*64 + chunk)*4 + st)*512 + (hi2*32 + l31r)*8 + j] =
                        f2bf(acc[tm][tn][r] + bv);
                }
        } else {
            // ---- V fragment scatter (f16) ----
            const int d = r0 - 128 + l15;
            const int dt = d >> 5, l31d = d & 31;
            #pragma unroll
            for (int tm = 0; tm < 4; ++tm)
                #pragma unroll
                for (int r = 0; r < 4; ++r) {
                    int row = m0 + wm*64 + tm*16 + quad*4 + r;
                    int bh = ((row >> 11) << 4) + h;
                    int chunk = (row >> 5) & 63;
                    int kc = row & 31, kh = kc >> 4, rem = kc & 15;
                    int hi2 = (rem >> 2) & 1;
                    int j = (rem & 3) | (((rem >> 3) & 1) << 2);
                    _Float16 hv = (_Float16)(acc[tm][tn][r] + bv);
                    Vf[(((size_t)(bh*64 + chunk)*2 + dt)*2 + kh)*512 + (hi2*32 + l31d)*8 + j] =
                        *(unsigned short*)&hv;
                }
        }
    }
}

// ---------------- stage 2: flash attention, ZERO-LDS, T15 1-deep pipeline ----------------
// R12: R11 (108.7us) + software pipeline: QK(it+1) issues BEFORE exp/PV(it).
// R11 post-mortem: still stall-bound (~4080 cyc/CU per iter round vs ~600 demand);
// the QK->exp->PV chain was serial WITHIN each iteration. Now each slot does
// QK(next chunk)->S_alt (no dependency on the pending exp/PV) then EXPPV(prev):
// the 4 QK MFMAs fill the matrix pipe while the previous chunk's 16 exp2/8 cvt_pk
// run on VALU/trans; PV queues behind QK. Serial chain -> max(matrix, valu).
// T15 per guide (+7-11% attn, m214v36). Named sA/sB + hand-unrolled 2-slot body
// (rule #20: no runtime-indexed S arrays -> no scratch). +16 VGPR (second S):
// peak ~140, fits the (256,3) cap of 168 (R11: 56 arch, no spill). Keep cap.
// Slot schedule (verified index-by-index):
//   prologue: QK(0)->sA [kf=c0 preloaded], LOAD_K(1); vf=c0 preloaded
//   m=0..31: QK(2m+1)->sB; LOAD_K(2m+2) if m<31; EXPPV(sA) [vf=c2m]; LOAD_V(2m+1);
//            if m<31 { QK(2m+2)->sA; LOAD_K(2m+3); } EXPPV(sB) [vf=c2m+1];
//            LOAD_V(2m+2) if m<31
//   -> QK chunks 0..63 each once; EXPPV chunks 0..63 each once, one slot later.
#define QK_STEP(S)                                                                  \
    {                                                                               \
        f32x16 _z = {};                                                             \
        __builtin_amdgcn_s_setprio(1);                                              \
        _z = __builtin_amdgcn_mfma_f32_32x32x16_bf16(kf[0], qf[0], _z, 0, 0, 0);    \
        _z = __builtin_amdgcn_mfma_f32_32x32x16_bf16(kf[1], qf[1], _z, 0, 0, 0);    \
        _z = __builtin_amdgcn_mfma_f32_32x32x16_bf16(kf[2], qf[2], _z, 0, 0, 0);    \
        _z = __builtin_amdgcn_mfma_f32_32x32x16_bf16(kf[3], qf[3], _z, 0, 0, 0);    \
        __builtin_amdgcn_s_setprio(0);                                              \
        S = _z;                                                                     \
    }
#define LOAD_K(C)                                                                   \
    {                                                                               \
        const unsigned short* kn = kfb + (size_t)(C)*4*512;                         \
        kf[0] = *(const bf16x8*)(kn + 0*512);                                       \
        kf[1] = *(const bf16x8*)(kn + 1*512);                                       \
        kf[2] = *(const bf16x8*)(kn + 2*512);                                       \
        kf[3] = *(const bf16x8*)(kn + 3*512);                                       \
    }
#define LOAD_V(C)                                                                   \
    {                                                                               \
        const unsigned short* vn = vfb + (size_t)(C)*4*512;                         \
        vf[0][0] = *(const f16x8*)(vn + 0*512);                                     \
        vf[0][1] = *(const f16x8*)(vn + 1*512);                                     \
        vf[1][0] = *(const f16x8*)(vn + 2*512);                                     \
        vf[1][1] = *(const f16x8*)(vn + 3*512);                                     \
    }
#define EXPPV(S)                                                                    \
    {                                                                               \
        uint32_t w0,w1,w2,w3,w4,w5,w6,w7;                                           \
        float p0,p1,p2,p3;                                                          \
        p0=exp2f(S[0]);  p1=exp2f(S[1]);  p2=exp2f(S[2]);  p3=exp2f(S[3]);          \
        lp += (p0+p1)+(p2+p3); w0=pkh(p0,p1); w1=pkh(p2,p3);                        \
        p0=exp2f(S[4]);  p1=exp2f(S[5]);  p2=exp2f(S[6]);  p3=exp2f(S[7]);          \
        lp += (p0+p1)+(p2+p3); w2=pkh(p0,p1); w3=pkh(p2,p3);                        \
        p0=exp2f(S[8]);  p1=exp2f(S[9]);  p2=exp2f(S[10]); p3=exp2f(S[11]);         \
        lp += (p0+p1)+(p2+p3); w4=pkh(p0,p1); w5=pkh(p2,p3);                        \
        p0=exp2f(S[12]); p1=exp2f(S[13]); p2=exp2f(S[14]); p3=exp2f(S[15]);         \
        lp += (p0+p1)+(p2+p3); w6=pkh(p0,p1); w7=pkh(p2,p3);                        \
        f16x8 pf0, pf1;                                                             \
        union { uint32_t u[4]; f16x8 v; } cc;                                       \
        cc.u[0]=w0; cc.u[1]=w1; cc.u[2]=w2; cc.u[3]=w3; pf0 = cc.v;                 \
        cc.u[0]=w4; cc.u[1]=w5; cc.u[2]=w6; cc.u[3]=w7; pf1 = cc.v;                 \
        __builtin_amdgcn_s_setprio(1);                                              \
        o0 = __builtin_amdgcn_mfma_f32_32x32x16_f16(vf[0][0], pf0, o0, 0, 0, 0);    \
        o1 = __builtin_amdgcn_mfma_f32_32x32x16_f16(vf[1][0], pf0, o1, 0, 0, 0);    \
        o0 = __builtin_amdgcn_mfma_f32_32x32x16_f16(vf[0][1], pf1, o0, 0, 0, 0);    \
        o1 = __builtin_amdgcn_mfma_f32_32x32x16_f16(vf[1][1], pf1, o1, 0, 0, 0);    \
        __builtin_amdgcn_s_setprio(0);                                              \
    }
__global__ __launch_bounds__(256, 3) void k_attn(
    const unsigned short* __restrict__ Qb,  // [8192][1024] bf16 (pre-scaled)
    const unsigned short* __restrict__ Kf,  // fragment layout bf16
    const unsigned short* __restrict__ Vf,  // fragment layout f16
    float* __restrict__ out)
{
    const int t = threadIdx.x;
    const int wave = t >> 6, lane = t & 63;
    const int l31 = lane & 31, hi = lane >> 5;
    const int bh = blockIdx.x, b = bh >> 4, h = bh & 15;
    const int q0 = blockIdx.y * 128 + wave * 32;

    const unsigned short* qrow = Qb + (size_t)(b*SEQ + q0 + l31)*1024 + h*64;
    const unsigned short* kfb  = Kf + (size_t)bh * 64*4*512 + lane*8;       // + (chunk*4+st)*512
    const unsigned short* vfb  = Vf + (size_t)bh * 64*2*2*512 + lane*8;     // + ((chunk*2+dt)*2+kh)*512

    // Q B-frags: n = q = q0+l31, elem j of frag st at global dk = st*16 + hi*8 + j.
    bf16x8 qf[4];
    #pragma unroll
    for (int st = 0; st < 4; ++st)
        qf[st] = *(const bf16x8*)(qrow + st*16 + hi*8);

    bf16x8 kf[4];
    f16x8  vf[2][2];
    LOAD_K(0)
    LOAD_V(0)

    f32x16 o0 = {}, o1 = {};   // O^T tiles: d = dt*32 + (reg&3)+8*(reg>>2)+4*hi, q = l31
    float lp = 0.f;
    f32x16 sA, sB;

    // prologue: QK(0) -> sA, then prefetch kf chunk 1
    QK_STEP(sA)
    LOAD_K(1)

    for (int m = 0; m < 32; ++m) {
        // slot A
        QK_STEP(sB)                    // chunk 2m+1
        if (m < 31) LOAD_K(2*m + 2)
        EXPPV(sA)                      // chunk 2m, vf = chunk 2m
        LOAD_V(2*m + 1)
        // slot B
        if (m < 31) {
            QK_STEP(sA)                // chunk 2m+2
            LOAD_K(2*m + 3)
        }
        EXPPV(sB)                      // chunk 2m+1, vf = chunk 2m+1
        if (m < 31) LOAD_V(2*m + 2)
    }

    // l: the two half-lanes of each q hold disjoint key sets
    float lt = lp + __shfl_xor(lp, 32);
    float rl = 1.0f / lt;

    // out[b, q, h*64 + d]; o0[4g+c] is at d = 8g + 4hi + c (c=0..3), o1 at d+32
    float* outb = out + (size_t)(b*SEQ + q0 + l31)*(NHEADS*DH) + h*DH + 4*hi;
    #pragma unroll
    for (int g = 0; g < 4; ++g) {
        float4 v0 = make_float4(o0[4*g]*rl, o0[4*g+1]*rl, o0[4*g+2]*rl, o0[4*g+3]*rl);
        float4 v1 = make_float4(o1[4*g]*rl, o1[4*g+1]*rl, o1[4*g+2]*rl, o1[4*g+3]*rl);
        *(float4*)(outb + 8*g)      = v0;
        *(float4*)(outb + 32 + 8*g) = v1;
    }
}

extern "C" void kernel_launch(void* const* d_in, const int* in_sizes, int n_in,
                              void* d_out, int out_size, void* d_ws, size_t ws_size,
                              hipStream_t stream) {
    const float* x    = (const float*)d_in[0];
    const float* W    = (const float*)d_in[1];
    const float* bias = (const float*)d_in[2];
    float* out = (float*)d_out;

    // workspace: 73.4 MB total
    unsigned short* xb = (unsigned short*)d_ws;                  // 16 MB
    unsigned short* Wt = xb + (size_t)MTOT * D_IN;               // 6 MB
    unsigned short* Qb = Wt + (size_t)NQKV * D_IN;               // 16 MB
    unsigned short* Kf = Qb + (size_t)MTOT * D_IN;               // 16 MB
    unsigned short* Vf = Kf + (size_t)MTOT * D_IN;               // 16 MB

    hipLaunchKernelGGL(k_convert_x,  dim3(MTOT*D_IN/4/256), dim3(256),    0, stream, x, xb);
    hipLaunchKernelGGL(k_convert_wt, dim3(NQKV/32, D_IN/32), dim3(32, 8), 0, stream, W, Wt);
    hipLaunchKernelGGL(k_gemm_qkv,   dim3(NQKV/128, MTOT/128), dim3(256), 0, stream, xb, Wt, bias, Qb, Kf, Vf);
    hipLaunchKernelGGL(k_attn,       dim3(BATCH*NHEADS, SEQ/128), dim3(256), 0, stream, Qb, Kf, Vf, out);
}